// Round 2
// baseline (6001.037 us; speedup 1.0000x reference)
//
#include <hip/hip_runtime.h>
#include <math.h>

#define T_ 12
#define N_ 2048
#define D_ 128
#define ND_ 262144            // N_*D_ = 2^18
#define TND_ 3145728L         // T_*ND_

// cos/sin(2*pi*k/12), exact table; cos(2*pi*f*t/12) == COS12[(f*t)%12]
__constant__ float COS12[12] = {
    1.0f, 0.8660254037844387f, 0.5f, 0.0f, -0.5f, -0.8660254037844387f,
    -1.0f, -0.8660254037844387f, -0.5f, 0.0f, 0.5f, 0.8660254037844387f};
__constant__ float SIN12[12] = {
    0.0f, 0.5f, 0.8660254037844387f, 1.0f, 0.8660254037844387f, 0.5f,
    0.0f, -0.5f, -0.8660254037844387f, -1.0f, -0.8660254037844387f, -0.5f};

// ---------------------------------------------------------------------------
// Generic fp32 tiled GEMM: C[M,N] = ACCop( act( alpha * A@B(^T)(+bias) ) )
// Tile 128x128, BK=8, 256 threads, 8x8 micro-tile per thread.
// ASRC: 0 = fp32 dense [M,K] (lda=K)
//       1 = "x transposed" view: A[m,k] = x_f32[bb, t, n, d] with
//           m = bb*2048 + n, k = t*128 + d   (conv_down input)
// BSRC: 0 = f32 W[N,K]  (C = A @ W^T, torch Linear weight layout)
//       2 = f32 B[K,N]  (C = A @ B,   e.g. o = S @ v; ld = N)
// ACT:  0 none, 1 relu, 2 gelu(exact)
// ACC:  0 overwrite, 1 C += r, 2 C -= r
// Requires: M%128==0, N%128==0, K%8==0.
// ---------------------------------------------------------------------------
template <int ASRC, int BSRC, int ACT, int ACC>
__global__ __launch_bounds__(256) void gemm_k(
    const float* __restrict__ Aptr, const float* __restrict__ Bptr,
    const float* __restrict__ bias, float* __restrict__ C,
    int M, int N, int K, float alpha, long sAb, long sBb, long sCb) {
  __shared__ float As[8][128];
  __shared__ float Bs[8][128];
  const int tid = threadIdx.x;
  const int tx = tid & 15;
  const int ty = tid >> 4;
  const int row0 = blockIdx.y * 128;
  const int col0 = blockIdx.x * 128;
  const int bz = blockIdx.z;

  float acc[8][8];
#pragma unroll
  for (int i = 0; i < 8; ++i)
#pragma unroll
    for (int j = 0; j < 8; ++j) acc[i][j] = 0.0f;

  const int lrow = tid >> 1;        // 0..127
  const int lkk = (tid & 1) * 4;    // 0 or 4

  for (int k0 = 0; k0 < K; k0 += 8) {
    // ---- stage A tile ----
    if (ASRC == 0) {
      const float* A = Aptr + sAb * bz;
      const float4 a4 = *(const float4*)(A + (long)(row0 + lrow) * K + (k0 + lkk));
      As[lkk + 0][lrow] = a4.x;
      As[lkk + 1][lrow] = a4.y;
      As[lkk + 2][lrow] = a4.z;
      As[lkk + 3][lrow] = a4.w;
    } else {
      const int m = row0 + lrow;
      const int bb = m >> 11;         // local batch
      const int nn = m & (N_ - 1);    // node
      const int kk = k0 + lkk;
      const int t = kk >> 7;
      const int d = kk & (D_ - 1);    // 4 consecutive d, same t
      const float4 a4 = *(const float4*)(Aptr + (long)(bb * T_ + t) * ND_ +
                                         (long)nn * D_ + d);
      As[lkk + 0][lrow] = a4.x;
      As[lkk + 1][lrow] = a4.y;
      As[lkk + 2][lrow] = a4.z;
      As[lkk + 3][lrow] = a4.w;
    }
    // ---- stage B tile ----
    if (BSRC == 0) {
      const float* W = Bptr + sBb * bz;
      const float4 b4 = *(const float4*)(W + (long)(col0 + lrow) * K + (k0 + lkk));
      Bs[lkk + 0][lrow] = b4.x;
      Bs[lkk + 1][lrow] = b4.y;
      Bs[lkk + 2][lrow] = b4.z;
      Bs[lkk + 3][lrow] = b4.w;
    } else {
      const float* Bm = Bptr + sBb * bz;
      const int col = tid & 127;
      const int kk4 = (tid >> 7) * 4;
#pragma unroll
      for (int j = 0; j < 4; ++j)
        Bs[kk4 + j][col] = Bm[(long)(k0 + kk4 + j) * N + col0 + col];
    }
    __syncthreads();
#pragma unroll
    for (int kk = 0; kk < 8; ++kk) {
      float a[8], b[8];
#pragma unroll
      for (int i = 0; i < 8; ++i) a[i] = As[kk][ty * 8 + i];
#pragma unroll
      for (int j = 0; j < 8; ++j) b[j] = Bs[kk][tx * 8 + j];
#pragma unroll
      for (int i = 0; i < 8; ++i)
#pragma unroll
        for (int j = 0; j < 8; ++j) acc[i][j] = fmaf(a[i], b[j], acc[i][j]);
    }
    __syncthreads();
  }

  // ---- epilogue ----
#pragma unroll
  for (int i = 0; i < 8; ++i) {
    const long row = row0 + ty * 8 + i;
    float* Crow = C + sCb * bz + row * (long)N + col0 + tx * 8;
#pragma unroll
    for (int j = 0; j < 8; ++j) {
      float r = acc[i][j] * alpha;
      if (bias != nullptr) r += bias[col0 + tx * 8 + j];
      if (ACT == 1) r = fmaxf(r, 0.0f);
      if (ACT == 2) r = 0.5f * r * (1.0f + erff(r * 0.7071067811865475f));
      if (ACC == 0)
        Crow[j] = r;
      else if (ACC == 1)
        Crow[j] += r;
      else
        Crow[j] -= r;
    }
  }
}

// ---------------------------------------------------------------------------
// conv_up GEMM2 fused with bias + residual + LayerNorm.
// A = u1 fp32 [M,1536], W = Wu2 f32 [1536,1536], bias = bu2.
// Block col index bx == t (BN=128 == one t-chunk == full d range), so each
// C row-slice is exactly one LayerNorm group; reduce across 16 lanes (tx).
// h1 = gemm + bias + x[bb,t,n,d]; hn = (h1-mu)/sqrt(var+eps)*gamma+beta
// written to hn[bb,t,n,d] (fp32).
// ---------------------------------------------------------------------------
__global__ __launch_bounds__(256) void gemm_ln_k(
    const float* __restrict__ A, const float* __restrict__ W,
    const float* __restrict__ bias, const float* __restrict__ x,
    const float* __restrict__ gamma, const float* __restrict__ beta,
    float* __restrict__ hn, int M) {
  const int K = 1536;
  __shared__ float As[8][128];
  __shared__ float Bs[8][128];
  const int tid = threadIdx.x;
  const int tx = tid & 15;
  const int ty = tid >> 4;
  const int row0 = blockIdx.y * 128;
  const int t = blockIdx.x;        // 0..11
  const int col0 = t * 128;

  float acc[8][8];
#pragma unroll
  for (int i = 0; i < 8; ++i)
#pragma unroll
    for (int j = 0; j < 8; ++j) acc[i][j] = 0.0f;

  const int lrow = tid >> 1;
  const int lkk = (tid & 1) * 4;

  for (int k0 = 0; k0 < K; k0 += 8) {
    const float4 a4 = *(const float4*)(A + (long)(row0 + lrow) * K + (k0 + lkk));
    As[lkk + 0][lrow] = a4.x;
    As[lkk + 1][lrow] = a4.y;
    As[lkk + 2][lrow] = a4.z;
    As[lkk + 3][lrow] = a4.w;
    const float4 b4 = *(const float4*)(W + (long)(col0 + lrow) * K + (k0 + lkk));
    Bs[lkk + 0][lrow] = b4.x;
    Bs[lkk + 1][lrow] = b4.y;
    Bs[lkk + 2][lrow] = b4.z;
    Bs[lkk + 3][lrow] = b4.w;
    __syncthreads();
#pragma unroll
    for (int kk = 0; kk < 8; ++kk) {
      float a[8], b[8];
#pragma unroll
      for (int i = 0; i < 8; ++i) a[i] = As[kk][ty * 8 + i];
#pragma unroll
      for (int j = 0; j < 8; ++j) b[j] = Bs[kk][tx * 8 + j];
#pragma unroll
      for (int i = 0; i < 8; ++i)
#pragma unroll
        for (int j = 0; j < 8; ++j) acc[i][j] = fmaf(a[i], b[j], acc[i][j]);
    }
    __syncthreads();
  }

#pragma unroll
  for (int i = 0; i < 8; ++i) {
    const int m = row0 + ty * 8 + i;
    const int bb = m >> 11;
    const int nn = m & (N_ - 1);
    const long base = (long)(bb * T_ + t) * ND_ + (long)nn * D_;
    const float* xrow = x + base;
    float h[8];
    float s1 = 0.0f, s2 = 0.0f;
#pragma unroll
    for (int j = 0; j < 8; ++j) {
      const int d = tx * 8 + j;
      float v = acc[i][j] + bias[col0 + d] + xrow[d];
      h[j] = v;
      s1 += v;
      s2 += v * v;
    }
    // reduce across the 16 lanes that share this row (same ty, tx 0..15)
#pragma unroll
    for (int msk = 1; msk < 16; msk <<= 1) {
      s1 += __shfl_xor(s1, msk);
      s2 += __shfl_xor(s2, msk);
    }
    const float mu = s1 * (1.0f / 128.0f);
    const float var = s2 * (1.0f / 128.0f) - mu * mu;
    const float rstd = rsqrtf(var + 1e-5f);
    float* hrow = hn + base;
#pragma unroll
    for (int j = 0; j < 8; ++j) {
      const int d = tx * 8 + j;
      hrow[d] = (h[j] - mu) * rstd * gamma[d] + beta[d];
    }
  }
}

// ---------------------------------------------------------------------------
// Row softmax over 2048 entries, in place. grid = (2048, CB), block = 256.
// ---------------------------------------------------------------------------
__global__ __launch_bounds__(256) void softmax_k(float* __restrict__ S) {
  const long row = (long)blockIdx.y * N_ + blockIdx.x;
  float* p = S + row * N_;
  const int tid = threadIdx.x;
  float v[8];
  float mx = -3.4e38f;
#pragma unroll
  for (int j = 0; j < 8; ++j) {
    v[j] = p[tid + 256 * j];
    mx = fmaxf(mx, v[j]);
  }
  __shared__ float red[256];
  red[tid] = mx;
  __syncthreads();
  for (int s = 128; s > 0; s >>= 1) {
    if (tid < s) red[tid] = fmaxf(red[tid], red[tid + s]);
    __syncthreads();
  }
  mx = red[0];
  __syncthreads();
  float sum = 0.0f;
#pragma unroll
  for (int j = 0; j < 8; ++j) {
    v[j] = expf(v[j] - mx);
    sum += v[j];
  }
  red[tid] = sum;
  __syncthreads();
  for (int s = 128; s > 0; s >>= 1) {
    if (tid < s) red[tid] += red[tid + s];
    __syncthreads();
  }
  const float inv = 1.0f / red[0];
#pragma unroll
  for (int j = 0; j < 8; ++j) p[tid + 256 * j] = v[j] * inv;
}

// ---------------------------------------------------------------------------
// rfft over T=12 (direct 12-point DFT). One thread per (bb, n, d).
// hn: [CB,12,2048,128] f32 -> re/im: [CB,7,2048,128] f32.
// ---------------------------------------------------------------------------
__global__ __launch_bounds__(256) void rfft_k(const float* __restrict__ hn,
                                              float* __restrict__ re,
                                              float* __restrict__ im) {
  const long i = (long)blockIdx.x * 256 + threadIdx.x;
  const int bb = (int)(i >> 18);
  const int nd = (int)(i & (ND_ - 1));
  float ht[12];
#pragma unroll
  for (int t = 0; t < 12; ++t) ht[t] = hn[((long)(bb * T_ + t) << 18) + nd];
#pragma unroll
  for (int f = 0; f < 7; ++f) {
    float sr = 0.0f, si = 0.0f;
#pragma unroll
    for (int t = 0; t < 12; ++t) {
      const int k = (f * t) % 12;
      sr = fmaf(ht[t], COS12[k], sr);
      si = fmaf(ht[t], SIN12[k], si);
    }
    const long off = ((long)(bb * 7 + f) << 18) + nd;
    re[off] = sr;
    im[off] = -si;
  }
}

// ---------------------------------------------------------------------------
// irfft (n=12) + residual, writes f32 output. One thread per (bb, n, d).
// Imag parts of DC/Nyquist bins dropped (numpy C2R semantics).
// ---------------------------------------------------------------------------
__global__ __launch_bounds__(256) void irfft_k(const float* __restrict__ hr,
                                               const float* __restrict__ hi,
                                               const float* __restrict__ x,
                                               float* __restrict__ out) {
  const long i = (long)blockIdx.x * 256 + threadIdx.x;
  const int bb = (int)(i >> 18);
  const int nd = (int)(i & (ND_ - 1));
  float r[7], m[7];
#pragma unroll
  for (int f = 0; f < 7; ++f) {
    const long off = ((long)(bb * 7 + f) << 18) + nd;
    r[f] = hr[off];
    m[f] = hi[off];
  }
#pragma unroll
  for (int t = 0; t < 12; ++t) {
    float s = r[0] + ((t & 1) ? -r[6] : r[6]);
#pragma unroll
    for (int f = 1; f < 6; ++f) {
      const int k = (f * t) % 12;
      s += 2.0f * (r[f] * COS12[k] - m[f] * SIN12[k]);
    }
    const long xi = ((long)(bb * T_ + t) << 18) + nd;
    out[xi] = s * (1.0f / 12.0f) + x[xi];
  }
}

// ---------------------------------------------------------------------------
// Host launcher. Workspace-adaptive: processes CB batches per pass, CB chosen
// as the largest of {16,8,4,2,1} whose fp32 intermediates fit ws_size.
// Per-batch footprint: 23,592,960 floats (90 MiB), with S and u1 aliased
// (S dead once o = S@v is computed, strictly before u1 is written).
// ---------------------------------------------------------------------------
extern "C" void kernel_launch(void* const* d_in, const int* in_sizes, int n_in,
                              void* d_out, int out_size, void* d_ws,
                              size_t ws_size, hipStream_t stream) {
  (void)in_sizes; (void)n_in; (void)out_size;
  const float* x   = (const float*)d_in[0];
  const float* Wd1 = (const float*)d_in[1];
  const float* bd1 = (const float*)d_in[2];
  const float* Wd2 = (const float*)d_in[3];
  const float* bd2 = (const float*)d_in[4];
  const float* Wq  = (const float*)d_in[5];
  const float* bq  = (const float*)d_in[6];
  const float* Wk  = (const float*)d_in[7];
  const float* bk  = (const float*)d_in[8];
  const float* Wv  = (const float*)d_in[9];
  const float* bv  = (const float*)d_in[10];
  const float* Wu1 = (const float*)d_in[11];
  const float* bu1 = (const float*)d_in[12];
  const float* Wu2 = (const float*)d_in[13];
  const float* bu2 = (const float*)d_in[14];
  const float* gamma = (const float*)d_in[15];
  const float* beta  = (const float*)d_in[16];
  const float* Wr1 = (const float*)d_in[17];
  const float* br1 = (const float*)d_in[18];
  const float* Wr2 = (const float*)d_in[19];
  const float* br2 = (const float*)d_in[20];
  const float* Wi1 = (const float*)d_in[21];
  const float* bi1 = (const float*)d_in[22];
  const float* Wi2 = (const float*)d_in[23];
  const float* bi2 = (const float*)d_in[24];
  float* out = (float*)d_out;

  // choose chunk size
  int CB = 1;
  const int cands[5] = {16, 8, 4, 2, 1};
  for (int ci = 0; ci < 5; ++ci) {
    if ((size_t)cands[ci] * 23592960ull * 4ull <= ws_size) { CB = cands[ci]; break; }
  }

  float* ws = (float*)d_ws;
  const long R = (long)CB * N_;       // conv rows per chunk
  const long F = (long)CB * 7 * N_;   // fft rows per chunk
  float* y1 = ws;
  float* y  = y1 + R * D_;
  float* q  = y  + R * D_;
  float* kk = q  + R * D_;
  float* v  = kk + R * D_;
  float* o  = v  + R * D_;
  float* S  = o  + R * D_;            // CB * 2048 * 2048
  float* u1 = S;                       // alias: S dead before u1 written
  float* hn = S + (long)CB * N_ * N_;  // R * 1536
  float* re = hn + R * 1536;
  float* im = re + F * D_;
  float* g1 = im + F * D_;
  float* g2 = g1 + F * D_;
  float* g3 = g2 + F * D_;
  float* g4 = g3 + F * D_;
  float* hr = g4 + F * D_;
  float* hi = hr + F * D_;

  const dim3 blk(256);
  const int M = (int)R;
  const int MF = (int)F;
  const float scale = 0.125f;  // 1/sqrt(D/2) = 1/sqrt(64)

  for (int c = 0; c < 16 / CB; ++c) {
    const int b0 = c * CB;
    const float* xc = x + (long)b0 * TND_;
    float* oc = out + (long)b0 * TND_;

    // conv_down: y1 = relu(xt @ Wd1^T + bd1); y = y1 @ Wd2^T + bd2
    gemm_k<1, 0, 1, 0><<<dim3(1, M / 128, 1), blk, 0, stream>>>(
        xc, Wd1, bd1, y1, M, 128, 1536, 1.0f, 0, 0, 0);
    gemm_k<0, 0, 0, 0><<<dim3(1, M / 128, 1), blk, 0, stream>>>(
        y1, Wd2, bd2, y, M, 128, 128, 1.0f, 0, 0, 0);
    // q, k, v
    gemm_k<0, 0, 0, 0><<<dim3(1, M / 128, 1), blk, 0, stream>>>(
        y, Wq, bq, q, M, 128, 128, 1.0f, 0, 0, 0);
    gemm_k<0, 0, 0, 0><<<dim3(1, M / 128, 1), blk, 0, stream>>>(
        y, Wk, bk, kk, M, 128, 128, 1.0f, 0, 0, 0);
    gemm_k<0, 0, 0, 0><<<dim3(1, M / 128, 1), blk, 0, stream>>>(
        y, Wv, bv, v, M, 128, 128, 1.0f, 0, 0, 0);
    // scores = softmax(q @ k^T * scale)  (k as W[N,K] => q @ k^T)
    gemm_k<0, 0, 0, 0><<<dim3(16, 16, CB), blk, 0, stream>>>(
        q, kk, nullptr, S, N_, N_, 128, scale, (long)ND_, (long)ND_,
        (long)N_ * N_);
    softmax_k<<<dim3(N_, CB), blk, 0, stream>>>(S);
    // o = S @ v
    gemm_k<0, 2, 0, 0><<<dim3(1, 16, CB), blk, 0, stream>>>(
        S, v, nullptr, o, N_, 128, N_, 1.0f, (long)N_ * N_, (long)ND_,
        (long)ND_);
    // conv_up: u1 = relu(o @ Wu1^T + bu1); then GEMM2 + residual + LN -> hn
    gemm_k<0, 0, 1, 0><<<dim3(12, M / 128, 1), blk, 0, stream>>>(
        o, Wu1, bu1, u1, M, 1536, 128, 1.0f, 0, 0, 0);
    gemm_ln_k<<<dim3(12, M / 128, 1), blk, 0, stream>>>(
        u1, Wu2, bu2, xc, gamma, beta, hn, M);
    // rfft over T
    const int total = CB * ND_;
    rfft_k<<<dim3(total / 256), blk, 0, stream>>>(hn, re, im);
    // four first-layer MLP GEMMs with exact GELU
    gemm_k<0, 0, 2, 0><<<dim3(1, MF / 128, 1), blk, 0, stream>>>(
        re, Wr1, br1, g1, MF, 128, 128, 1.0f, 0, 0, 0);
    gemm_k<0, 0, 2, 0><<<dim3(1, MF / 128, 1), blk, 0, stream>>>(
        im, Wi1, bi1, g2, MF, 128, 128, 1.0f, 0, 0, 0);
    gemm_k<0, 0, 2, 0><<<dim3(1, MF / 128, 1), blk, 0, stream>>>(
        re, Wi1, bi1, g3, MF, 128, 128, 1.0f, 0, 0, 0);
    gemm_k<0, 0, 2, 0><<<dim3(1, MF / 128, 1), blk, 0, stream>>>(
        im, Wr1, br1, g4, MF, 128, 128, 1.0f, 0, 0, 0);
    // hr = (g1@Wr2 + br2) - (g2@Wi2 + bi2)
    gemm_k<0, 0, 0, 0><<<dim3(1, MF / 128, 1), blk, 0, stream>>>(
        g1, Wr2, br2, hr, MF, 128, 128, 1.0f, 0, 0, 0);
    gemm_k<0, 0, 0, 2><<<dim3(1, MF / 128, 1), blk, 0, stream>>>(
        g2, Wi2, bi2, hr, MF, 128, 128, 1.0f, 0, 0, 0);
    // hi = (g3@Wi2 + bi2) + (g4@Wr2 + br2)
    gemm_k<0, 0, 0, 0><<<dim3(1, MF / 128, 1), blk, 0, stream>>>(
        g3, Wi2, bi2, hi, MF, 128, 128, 1.0f, 0, 0, 0);
    gemm_k<0, 0, 0, 1><<<dim3(1, MF / 128, 1), blk, 0, stream>>>(
        g4, Wr2, br2, hi, MF, 128, 128, 1.0f, 0, 0, 0);
    // irfft + residual -> f32 out
    irfft_k<<<dim3(total / 256), blk, 0, stream>>>(hr, hi, xc, oc);
  }
}

// Round 3
// 2094.021 us; speedup vs baseline: 2.8658x; 2.8658x over previous
//
#include <hip/hip_runtime.h>
#include <math.h>

#define T_ 12
#define N_ 2048
#define D_ 128
#define ND_ 262144            // N_*D_ = 2^18
#define TND_ 3145728L         // T_*ND_

typedef __attribute__((ext_vector_type(8))) short short8;   // 8 bf16 (4 VGPRs)
typedef __attribute__((ext_vector_type(4))) float f32x4;

__device__ __forceinline__ ushort f2b(float f) {            // fp32 -> bf16 RNE
  unsigned u = __float_as_uint(f);
  u += 0x7fffu + ((u >> 16) & 1u);
  return (ushort)(u >> 16);
}
__device__ __forceinline__ float b2f(ushort s) {
  return __uint_as_float(((unsigned)s) << 16);
}

// cos/sin(2*pi*k/12); cos(2*pi*f*t/12) == COS12[(f*t)%12]
__constant__ float COS12[12] = {
    1.0f, 0.8660254037844387f, 0.5f, 0.0f, -0.5f, -0.8660254037844387f,
    -1.0f, -0.8660254037844387f, -0.5f, 0.0f, 0.5f, 0.8660254037844387f};
__constant__ float SIN12[12] = {
    0.0f, 0.5f, 0.8660254037844387f, 1.0f, 0.8660254037844387f, 0.5f,
    0.0f, -0.5f, -0.8660254037844387f, -1.0f, -0.8660254037844387f, -0.5f};

// ---------------------------------------------------------------------------
// bf16 MFMA GEMM: C[M,N] = ACT( alpha * A@B^T + bias ), A bf16 [M,K] (lda),
// B bf16 [N,K] (ldb, torch Linear weight layout). Tile 128x128, BK=32,
// 4 waves, each wave 32(M)x128(N) = 2x8 MFMAs of 16x16x32.
// LDS tiles in MFMA-fragment order: block ri holds rows ri*16+(l&15),
// k (l>>4)*8..+7 at offset ri*512 + l*8 (lane-contiguous 16B: 2-way bank
// alias only => conflict-free per m136).
// ACT: 0 none, 1 relu, 2 gelu(exact). OUT: 0 f32, 1 bf16, 2 bf16 transposed
// (C^T, for vT). off0/off1: epilogue col remap c += (c<128 ? off0 : off1)
// (used for the concat FFT-MLP outputs; 0,0 otherwise).
// Requires M%128==0, N%128==0, K%32==0.
// ---------------------------------------------------------------------------
template <int ACT, int OUT>
__global__ __launch_bounds__(256) void mgemm(
    const ushort* __restrict__ A, const ushort* __restrict__ B,
    const float* __restrict__ bias, void* __restrict__ Cv,
    int K, int lda, int ldb, int ldc, float alpha,
    long sAb, long sBb, long sCb, int off0, int off1) {
  __shared__ ushort As[4096];
  __shared__ ushort Bs[4096];
  const int tid = threadIdx.x;
  const int w = tid >> 6;
  const int l = tid & 63;
  const int lr = l & 15;        // fragment row/col within 16
  const int lg = l >> 4;        // k-group (0..3)
  const int row0 = blockIdx.y * 128;
  const int col0 = blockIdx.x * 128;
  const ushort* Ap = A + sAb * blockIdx.z;
  const ushort* Bp = B + sBb * blockIdx.z;

  f32x4 acc[2][8];
#pragma unroll
  for (int i = 0; i < 2; ++i)
#pragma unroll
    for (int j = 0; j < 8; ++j) acc[i][j] = (f32x4){0.f, 0.f, 0.f, 0.f};

  const int ba = w, bb2 = w + 4;   // each wave stages 2 A-blocks + 2 B-blocks
  for (int k0 = 0; k0 < K; k0 += 32) {
    const float4 a1v = *(const float4*)(Ap + (long)(row0 + ba * 16 + lr) * lda + k0 + lg * 8);
    const float4 a2v = *(const float4*)(Ap + (long)(row0 + bb2 * 16 + lr) * lda + k0 + lg * 8);
    const float4 b1v = *(const float4*)(Bp + (long)(col0 + ba * 16 + lr) * ldb + k0 + lg * 8);
    const float4 b2v = *(const float4*)(Bp + (long)(col0 + bb2 * 16 + lr) * ldb + k0 + lg * 8);
    *(float4*)(As + ba * 512 + l * 8) = a1v;
    *(float4*)(As + bb2 * 512 + l * 8) = a2v;
    *(float4*)(Bs + ba * 512 + l * 8) = b1v;
    *(float4*)(Bs + bb2 * 512 + l * 8) = b2v;
    __syncthreads();
    const short8 a0 = *(const short8*)(As + (w * 2 + 0) * 512 + l * 8);
    const short8 a1 = *(const short8*)(As + (w * 2 + 1) * 512 + l * 8);
#pragma unroll
    for (int ni = 0; ni < 8; ++ni) {
      const short8 bfr = *(const short8*)(Bs + ni * 512 + l * 8);
      acc[0][ni] = __builtin_amdgcn_mfma_f32_16x16x32_bf16(a0, bfr, acc[0][ni], 0, 0, 0);
      acc[1][ni] = __builtin_amdgcn_mfma_f32_16x16x32_bf16(a1, bfr, acc[1][ni], 0, 0, 0);
    }
    __syncthreads();
  }

  // epilogue: C/D layout col=l&15, row=(l>>4)*4+reg  [m89/m91]
  const long Cz = sCb * blockIdx.z;
#pragma unroll
  for (int mi = 0; mi < 2; ++mi) {
    const int grow0 = row0 + w * 32 + mi * 16 + lg * 4;
    if (OUT == 2) {
      ushort* C = (ushort*)Cv;
#pragma unroll
      for (int ni = 0; ni < 8; ++ni) {
        const int c = col0 + ni * 16 + lr;
        const float bv = bias ? bias[c] : 0.f;
        ushort4 pk;
        float v0 = acc[mi][ni][0] * alpha + bv;
        float v1 = acc[mi][ni][1] * alpha + bv;
        float v2 = acc[mi][ni][2] * alpha + bv;
        float v3 = acc[mi][ni][3] * alpha + bv;
        if (ACT == 1) { v0 = fmaxf(v0, 0.f); v1 = fmaxf(v1, 0.f); v2 = fmaxf(v2, 0.f); v3 = fmaxf(v3, 0.f); }
        pk.x = f2b(v0); pk.y = f2b(v1); pk.z = f2b(v2); pk.w = f2b(v3);
        *(ushort4*)(C + (long)c * ldc + grow0) = pk;
      }
    } else {
#pragma unroll
      for (int ni = 0; ni < 8; ++ni) {
        const int c = col0 + ni * 16 + lr;
        const float bv = bias ? bias[c] : 0.f;
        const int cm = c + (c < 128 ? off0 : off1);
#pragma unroll
        for (int r = 0; r < 4; ++r) {
          float v = acc[mi][ni][r] * alpha + bv;
          if (ACT == 1) v = fmaxf(v, 0.f);
          if (ACT == 2) v = 0.5f * v * (1.0f + erff(v * 0.7071067811865475f));
          const long off = Cz + (long)(grow0 + r) * ldc + cm;
          if (OUT == 0) ((float*)Cv)[off] = v;
          else ((ushort*)Cv)[off] = f2b(v);
        }
      }
    }
  }
}

// ---------------------------------------------------------------------------
// conv_up GEMM2 (A=u1 bf16 [M,1536], B=Wu2b bf16 [1536,1536]) fused with
// bias + residual(x fp32) + LayerNorm -> hn fp32 [bb,t,n,d].
// blockIdx.x == t, so each output row-slice is one full LN group (d=128),
// held by the 16 lanes sharing lg => shuffle-reduce masks 1,2,4,8.
// ---------------------------------------------------------------------------
__global__ __launch_bounds__(256) void mgemm_ln(
    const ushort* __restrict__ A, const ushort* __restrict__ B,
    const float* __restrict__ bias, const float* __restrict__ x,
    const float* __restrict__ gamma, const float* __restrict__ beta,
    float* __restrict__ hn) {
  const int K = 1536;
  __shared__ ushort As[4096];
  __shared__ ushort Bs[4096];
  const int tid = threadIdx.x;
  const int w = tid >> 6;
  const int l = tid & 63;
  const int lr = l & 15;
  const int lg = l >> 4;
  const int row0 = blockIdx.y * 128;
  const int t = blockIdx.x;
  const int col0 = t * 128;

  f32x4 acc[2][8];
#pragma unroll
  for (int i = 0; i < 2; ++i)
#pragma unroll
    for (int j = 0; j < 8; ++j) acc[i][j] = (f32x4){0.f, 0.f, 0.f, 0.f};

  const int ba = w, bb2 = w + 4;
  for (int k0 = 0; k0 < K; k0 += 32) {
    const float4 a1v = *(const float4*)(A + (long)(row0 + ba * 16 + lr) * K + k0 + lg * 8);
    const float4 a2v = *(const float4*)(A + (long)(row0 + bb2 * 16 + lr) * K + k0 + lg * 8);
    const float4 b1v = *(const float4*)(B + (long)(col0 + ba * 16 + lr) * K + k0 + lg * 8);
    const float4 b2v = *(const float4*)(B + (long)(col0 + bb2 * 16 + lr) * K + k0 + lg * 8);
    *(float4*)(As + ba * 512 + l * 8) = a1v;
    *(float4*)(As + bb2 * 512 + l * 8) = a2v;
    *(float4*)(Bs + ba * 512 + l * 8) = b1v;
    *(float4*)(Bs + bb2 * 512 + l * 8) = b2v;
    __syncthreads();
    const short8 a0 = *(const short8*)(As + (w * 2 + 0) * 512 + l * 8);
    const short8 a1 = *(const short8*)(As + (w * 2 + 1) * 512 + l * 8);
#pragma unroll
    for (int ni = 0; ni < 8; ++ni) {
      const short8 bfr = *(const short8*)(Bs + ni * 512 + l * 8);
      acc[0][ni] = __builtin_amdgcn_mfma_f32_16x16x32_bf16(a0, bfr, acc[0][ni], 0, 0, 0);
      acc[1][ni] = __builtin_amdgcn_mfma_f32_16x16x32_bf16(a1, bfr, acc[1][ni], 0, 0, 0);
    }
    __syncthreads();
  }

#pragma unroll
  for (int mi = 0; mi < 2; ++mi) {
#pragma unroll
    for (int r = 0; r < 4; ++r) {
      const int gr = row0 + w * 32 + mi * 16 + lg * 4 + r;
      const int bb = gr >> 11;
      const int nn = gr & 2047;
      const long base = ((long)(bb * 12 + t) << 18) + (long)nn * 128;
      float h[8];
      float s1 = 0.f, s2 = 0.f;
#pragma unroll
      for (int ni = 0; ni < 8; ++ni) {
        const int d = ni * 16 + lr;
        const float v = acc[mi][ni][r] + bias[col0 + d] + x[base + d];
        h[ni] = v;
        s1 += v;
        s2 += v * v;
      }
#pragma unroll
      for (int m = 1; m < 16; m <<= 1) {
        s1 += __shfl_xor(s1, m);
        s2 += __shfl_xor(s2, m);
      }
      const float mu = s1 * (1.f / 128.f);
      const float rstd = rsqrtf(s2 * (1.f / 128.f) - mu * mu + 1e-5f);
#pragma unroll
      for (int ni = 0; ni < 8; ++ni) {
        const int d = ni * 16 + lr;
        hn[base + d] = (h[ni] - mu) * rstd * gamma[d] + beta[d];
      }
    }
  }
}

// ---------------------------------------------------------------------------
// Row softmax over 2048 fp32 logits -> bf16 probabilities.
// grid = (2048, CB), block = 256.
// ---------------------------------------------------------------------------
__global__ __launch_bounds__(256) void softmax_k(const float* __restrict__ S,
                                                 ushort* __restrict__ P) {
  const long row = ((long)blockIdx.y * N_ + blockIdx.x) * N_;
  const float* p = S + row;
  const int tid = threadIdx.x;
  float v[8];
  float mx = -3.4e38f;
#pragma unroll
  for (int j = 0; j < 8; ++j) {
    v[j] = p[tid + 256 * j];
    mx = fmaxf(mx, v[j]);
  }
  __shared__ float red[256];
  red[tid] = mx;
  __syncthreads();
  for (int s = 128; s > 0; s >>= 1) {
    if (tid < s) red[tid] = fmaxf(red[tid], red[tid + s]);
    __syncthreads();
  }
  mx = red[0];
  __syncthreads();
  float sum = 0.0f;
#pragma unroll
  for (int j = 0; j < 8; ++j) {
    v[j] = expf(v[j] - mx);
    sum += v[j];
  }
  red[tid] = sum;
  __syncthreads();
  for (int s = 128; s > 0; s >>= 1) {
    if (tid < s) red[tid] += red[tid + s];
    __syncthreads();
  }
  const float inv = 1.0f / red[0];
#pragma unroll
  for (int j = 0; j < 8; ++j) P[row + tid + 256 * j] = f2b(v[j] * inv);
}

// rfft over T=12: hn fp32 [CB,12,2048,128] -> re/im bf16 [CB,7,2048,128]
__global__ __launch_bounds__(256) void rfft_k(const float* __restrict__ hn,
                                              ushort* __restrict__ re,
                                              ushort* __restrict__ im) {
  const long i = (long)blockIdx.x * 256 + threadIdx.x;
  const int bb = (int)(i >> 18);
  const int nd = (int)(i & (ND_ - 1));
  float ht[12];
#pragma unroll
  for (int t = 0; t < 12; ++t) ht[t] = hn[((long)(bb * T_ + t) << 18) + nd];
#pragma unroll
  for (int f = 0; f < 7; ++f) {
    float sr = 0.0f, si = 0.0f;
#pragma unroll
    for (int t = 0; t < 12; ++t) {
      const int k = (f * t) % 12;
      sr = fmaf(ht[t], COS12[k], sr);
      si = fmaf(ht[t], SIN12[k], si);
    }
    const long off = ((long)(bb * 7 + f) << 18) + nd;
    re[off] = f2b(sr);
    im[off] = f2b(-si);
  }
}

// irfft (n=12, numpy C2R: imag of DC/Nyquist dropped) + residual -> fp32 out
__global__ __launch_bounds__(256) void irfft_k(const float* __restrict__ hr,
                                               const float* __restrict__ hi,
                                               const float* __restrict__ x,
                                               float* __restrict__ out) {
  const long i = (long)blockIdx.x * 256 + threadIdx.x;
  const int bb = (int)(i >> 18);
  const int nd = (int)(i & (ND_ - 1));
  float r[7], m[7];
#pragma unroll
  for (int f = 0; f < 7; ++f) {
    const long off = ((long)(bb * 7 + f) << 18) + nd;
    r[f] = hr[off];
    m[f] = hi[off];
  }
#pragma unroll
  for (int t = 0; t < 12; ++t) {
    float s = r[0] + ((t & 1) ? -r[6] : r[6]);
#pragma unroll
    for (int f = 1; f < 6; ++f) {
      const int k = (f * t) % 12;
      s += 2.0f * (r[f] * COS12[k] - m[f] * SIN12[k]);
    }
    const long xi = ((long)(bb * T_ + t) << 18) + nd;
    out[xi] = s * (1.0f / 12.0f) + x[xi];
  }
}

// x fp32 [CB,12,2048,128] -> xt bf16 [CB*2048, 1536] (transposed conv_down in)
__global__ __launch_bounds__(256) void xt_k(const float* __restrict__ x,
                                            ushort* __restrict__ xt) {
  const long i = (long)blockIdx.x * 256 + threadIdx.x;
  const int d = (int)(i & 127);
  const long r = i >> 7;
  const int nn = (int)(r & 2047);
  const long r2 = r >> 11;
  const int t = (int)(r2 % 12);
  const int bb = (int)(r2 / 12);
  xt[((long)bb * 2048 + nn) * 1536 + t * 128 + d] = f2b(x[i]);
}

// ---------------------------------------------------------------------------
// Weight prep: fp32 -> bf16 with concat/sign-fold fusions + bias combos.
// Weight region (ushort elems):
//   Wd1b@0(196608) Wd2b@196608(16384) Wqkb@212992(32768=[Wq|Wk])
//   Wvb@245760(16384) Wu1b@262144(196608) Wu2b@458752(2359296)
//   W13b@2818048(32768=[Wr1|Wi1]) W24b@2850816(32768=[Wi1|Wr1])
//   Whrb@2883584(32768: [n][k]: k<128?Wr2:-Wi2)  Whib@2916352(32768: Wi2|Wr2)
// Bias region (f32): bqk@0(256) b13@256(256) b24@512(256) bhr@768(128) bhi@896(128)
// ---------------------------------------------------------------------------
__global__ __launch_bounds__(256) void prep_k(
    const float* Wd1, const float* Wd2, const float* Wq, const float* Wk,
    const float* Wv, const float* Wu1, const float* Wu2, const float* Wr1,
    const float* Wr2, const float* Wi1, const float* Wi2,
    const float* bq, const float* bk, const float* br1, const float* bi1,
    const float* br2, const float* bi2,
    ushort* __restrict__ wws, float* __restrict__ bws) {
  const long i = (long)blockIdx.x * 256 + threadIdx.x;
  if (i < 256) bws[i] = (i < 128) ? bq[i] : bk[i - 128];
  else if (i < 512) { const int j = i - 256; bws[i] = (j < 128) ? br1[j] : bi1[j - 128]; }
  else if (i < 768) { const int j = i - 512; bws[i] = (j < 128) ? bi1[j] : br1[j - 128]; }
  else if (i < 896) { const int j = i - 768; bws[i] = br2[j] - bi2[j]; }
  else if (i < 1024) { const int j = i - 896; bws[i] = bi2[j] + br2[j]; }
  if (i >= 2949120) return;
  float v;
  if (i < 196608) v = Wd1[i];
  else if (i < 212992) v = Wd2[i - 196608];
  else if (i < 245760) { const long j = i - 212992; v = (j < 16384) ? Wq[j] : Wk[j - 16384]; }
  else if (i < 262144) v = Wv[i - 245760];
  else if (i < 458752) v = Wu1[i - 262144];
  else if (i < 2818048) v = Wu2[i - 458752];
  else if (i < 2850816) { const long j = i - 2818048; v = (j < 16384) ? Wr1[j] : Wi1[j - 16384]; }
  else if (i < 2883584) { const long j = i - 2850816; v = (j < 16384) ? Wi1[j] : Wr1[j - 16384]; }
  else if (i < 2916352) {
    const long j = i - 2883584; const int n = (int)(j >> 8), k = (int)(j & 255);
    v = (k < 128) ? Wr2[n * 128 + k] : -Wi2[n * 128 + k - 128];
  } else {
    const long j = i - 2916352; const int n = (int)(j >> 8), k = (int)(j & 255);
    v = (k < 128) ? Wi2[n * 128 + k] : Wr2[n * 128 + k - 128];
  }
  wws[i] = f2b(v);
}

// ---------------------------------------------------------------------------
extern "C" void kernel_launch(void* const* d_in, const int* in_sizes, int n_in,
                              void* d_out, int out_size, void* d_ws,
                              size_t ws_size, hipStream_t stream) {
  (void)in_sizes; (void)n_in; (void)out_size;
  const float* x   = (const float*)d_in[0];
  const float* Wd1 = (const float*)d_in[1];
  const float* bd1 = (const float*)d_in[2];
  const float* Wd2 = (const float*)d_in[3];
  const float* bd2 = (const float*)d_in[4];
  const float* Wq  = (const float*)d_in[5];
  const float* bq  = (const float*)d_in[6];
  const float* Wk  = (const float*)d_in[7];
  const float* bk  = (const float*)d_in[8];
  const float* Wv  = (const float*)d_in[9];
  const float* bv  = (const float*)d_in[10];
  const float* Wu1 = (const float*)d_in[11];
  const float* bu1 = (const float*)d_in[12];
  const float* Wu2 = (const float*)d_in[13];
  const float* bu2 = (const float*)d_in[14];
  const float* gamma = (const float*)d_in[15];
  const float* beta  = (const float*)d_in[16];
  const float* Wr1 = (const float*)d_in[17];
  const float* br1 = (const float*)d_in[18];
  const float* Wr2 = (const float*)d_in[19];
  const float* br2 = (const float*)d_in[20];
  const float* Wi1 = (const float*)d_in[21];
  const float* bi1 = (const float*)d_in[22];
  const float* Wi2 = (const float*)d_in[23];
  const float* bi2 = (const float*)d_in[24];
  float* out = (float*)d_out;

  // ---- workspace carve-up ----
  float* bws = (float*)d_ws;                   // 1024 f32
  ushort* wws = (ushort*)(bws + 1024);         // 2949120 ushort
  const size_t kFixed = 1024 * 4 + 2949120 * 2;   // 5902336 B
  const size_t kPerBatch = 90177536;              // bytes (see buffer list)
  int CB = 1;
  const int cands[5] = {16, 8, 4, 2, 1};
  for (int ci = 0; ci < 5; ++ci)
    if (kFixed + (size_t)cands[ci] * kPerBatch <= ws_size) { CB = cands[ci]; break; }

  char* base = (char*)d_ws + kFixed;
  const long R = (long)CB * N_;            // conv rows per chunk
  const long Fr = (long)CB * 7 * N_;       // fft rows per chunk
  ushort* xt  = (ushort*)base;             // CB*3145728
  ushort* y1  = xt  + CB * 3145728L;       // R*128
  ushort* y   = y1  + R * 128;             // R*128
  ushort* qkb = y   + R * 128;             // R*256
  ushort* vT  = qkb + R * 256;             // 128*R
  ushort* P   = vT  + R * 128;             // CB*2048*2048
  ushort* o   = P   + (long)CB * N_ * N_;  // R*128
  ushort* u1  = o   + R * 128;             // R*1536
  ushort* re  = u1  + R * 1536;            // Fr*128
  ushort* im  = re  + Fr * 128;            // Fr*128
  ushort* G   = im  + Fr * 128;            // Fr*512
  float*  S   = (float*)(G + Fr * 512);    // CB*2048*2048
  float*  hn  = S   + (long)CB * N_ * N_;  // R*1536
  float*  hr  = hn  + R * 1536;            // Fr*128
  float*  hi  = hr  + Fr * 128;            // Fr*128

  const dim3 blk(256);
  const float scale = 0.125f;              // 1/sqrt(D/2)

  // weight prep (once per call; ~6 MB)
  prep_k<<<dim3(11520), blk, 0, stream>>>(Wd1, Wd2, Wq, Wk, Wv, Wu1, Wu2,
                                          Wr1, Wr2, Wi1, Wi2, bq, bk, br1,
                                          bi1, br2, bi2, wws, bws);
  ushort* Wd1b = wws;
  ushort* Wd2b = wws + 196608;
  ushort* Wqkb = wws + 212992;
  ushort* Wvb  = wws + 245760;
  ushort* Wu1b = wws + 262144;
  ushort* Wu2b = wws + 458752;
  ushort* W13b = wws + 2818048;
  ushort* W24b = wws + 2850816;
  ushort* Whrb = wws + 2883584;
  ushort* Whib = wws + 2916352;
  float* bqk = bws;
  float* b13 = bws + 256;
  float* b24 = bws + 512;
  float* bhr = bws + 768;
  float* bhi = bws + 896;

  for (int c = 0; c < 16 / CB; ++c) {
    const int b0 = c * CB;
    const float* xc = x + (long)b0 * TND_;
    float* oc = out + (long)b0 * TND_;
    const int GY = CB * 16;     // R/128
    const int GF = CB * 112;    // Fr/128

    // x -> xt (bf16 transposed view)
    xt_k<<<dim3(CB * 12288), blk, 0, stream>>>(xc, xt);
    // conv_down: y1 = relu(xt@Wd1^T+bd1); y = y1@Wd2^T+bd2
    mgemm<1, 1><<<dim3(1, GY), blk, 0, stream>>>(
        xt, Wd1b, bd1, y1, 1536, 1536, 1536, 128, 1.f, 0, 0, 0, 0, 0);
    mgemm<0, 1><<<dim3(1, GY), blk, 0, stream>>>(
        y1, Wd2b, bd2, y, 128, 128, 128, 128, 1.f, 0, 0, 0, 0, 0);
    // [q|k] and v^T
    mgemm<0, 1><<<dim3(2, GY), blk, 0, stream>>>(
        y, Wqkb, bqk, qkb, 128, 128, 128, 256, 1.f, 0, 0, 0, 0, 0);
    mgemm<0, 2><<<dim3(1, GY), blk, 0, stream>>>(
        y, Wvb, bv, vT, 128, 128, 128, (int)R, 1.f, 0, 0, 0, 0, 0);
    // logits S = 0.125 * q@k^T (fp32)
    mgemm<0, 0><<<dim3(16, 16, CB), blk, 0, stream>>>(
        qkb, qkb + 128, nullptr, S, 128, 256, 256, 2048, scale,
        524288, 524288, 4194304, 0, 0);
    softmax_k<<<dim3(N_, CB), blk, 0, stream>>>(S, P);
    // o = P @ v  (B = vT as W[N=128][K=2048])
    mgemm<0, 1><<<dim3(1, 16, CB), blk, 0, stream>>>(
        P, vT, nullptr, o, 2048, 2048, (int)R, 128, 1.f,
        4194304, 2048, 262144, 0, 0);
    // conv_up: u1 = relu(o@Wu1^T+bu1); GEMM2+residual+LN -> hn
    mgemm<1, 1><<<dim3(12, GY), blk, 0, stream>>>(
        o, Wu1b, bu1, u1, 128, 128, 128, 1536, 1.f, 0, 0, 0, 0, 0);
    mgemm_ln<<<dim3(12, GY), blk, 0, stream>>>(u1, Wu2b, bu2, xc, gamma, beta, hn);
    // rfft
    rfft_k<<<dim3(CB * 1024), blk, 0, stream>>>(hn, re, im);
    // FFT MLP layer 1 (concat): re -> [g1|g3], im -> [g2|g4] in G[M][512]
    mgemm<2, 1><<<dim3(2, GF), blk, 0, stream>>>(
        re, W13b, b13, G, 128, 128, 128, 512, 1.f, 0, 0, 0, 0, 128);
    mgemm<2, 1><<<dim3(2, GF), blk, 0, stream>>>(
        im, W24b, b24, G, 128, 128, 128, 512, 1.f, 0, 0, 0, 128, 256);
    // FFT MLP layer 2 (K=256 concat, sign-folded): hr, hi fp32
    mgemm<0, 0><<<dim3(1, GF), blk, 0, stream>>>(
        G, Whrb, bhr, hr, 256, 512, 256, 128, 1.f, 0, 0, 0, 0, 0);
    mgemm<0, 0><<<dim3(1, GF), blk, 0, stream>>>(
        G + 256, Whib, bhi, hi, 256, 512, 256, 128, 1.f, 0, 0, 0, 0, 0);
    // irfft + residual
    irfft_k<<<dim3(CB * 1024), blk, 0, stream>>>(hr, hi, xc, oc);
  }
}